// Round 6
// baseline (149.249 us; speedup 1.0000x reference)
//
#include <hip/hip_runtime.h>
#include <hip/hip_bf16.h>
#include <math.h>

// B=8, Cin=Cout=128, H=W=64, K=3, S=1, P=1
// ws layout (total 8,757,248 B < proven-safe 10,747,904 B):
//   wT    bf16 [9][128 co][128 c]  @ 0        (294,912 B)
//   woffT bf16 [9][32 oc][128 c]   @ 294,912  ( 73,728 B)  oc>=18 zero
//   xT    bf16 [8][64][64][128]    @ 368,640  (8,388,608 B)

typedef short bf16x8 __attribute__((ext_vector_type(8)));
typedef float f32x4  __attribute__((ext_vector_type(4)));

__device__ __forceinline__ unsigned short f2bf(float f) {
    unsigned u = __float_as_uint(f);
    u += 0x7fffu + ((u >> 16) & 1u);           // RNE
    return (unsigned short)(u >> 16);
}
__device__ __forceinline__ float bflo(unsigned u) { return __uint_as_float(u << 16); }
__device__ __forceinline__ float bfhi(unsigned u) { return __uint_as_float(u & 0xffff0000u); }

// ------------------------------------------------------------------
// Kernel P: repack w / w_offset into MFMA-fragment-ready bf16.
// ------------------------------------------------------------------
__global__ __launch_bounds__(256) void prep_weights(
    const float* __restrict__ w, const float* __restrict__ woff,
    unsigned short* __restrict__ wT, unsigned short* __restrict__ woffT) {
    int idx = blockIdx.x * 256 + threadIdx.x;
    if (idx < 147456) {
        int c  = idx & 127;
        int co = (idx >> 7) & 127;
        int kk = idx >> 14;
        wT[idx] = f2bf(w[co * 1152 + c * 9 + kk]);
    }
    if (idx < 36864) {
        int c  = idx & 127;
        int oc = (idx >> 7) & 31;
        int kk = idx >> 12;
        woffT[idx] = (oc < 18) ? f2bf(woff[oc * 1152 + c * 9 + kk]) : (unsigned short)0;
    }
}

// ------------------------------------------------------------------
// Kernel A: NCHW fp32 -> NHWC bf16 (pair-packed uint writes).
// ------------------------------------------------------------------
__global__ __launch_bounds__(256) void transpose_nchw_nhwc(
    const float* __restrict__ x, unsigned* __restrict__ xT) {
    __shared__ float tile[128][65];
    int bh = blockIdx.x;                 // b*64 + h
    int b = bh >> 6, h = bh & 63;
    const float* src = x + b * 524288 + h * 64;
    for (int idx = threadIdx.x; idx < 8192; idx += 256) {
        int c = idx >> 6, ww = idx & 63;
        tile[c][ww] = src[c * 4096 + ww];
    }
    __syncthreads();
    unsigned* dst = xT + (size_t)bh * 4096;   // [w][c/2] as uint
    for (int idx = threadIdx.x; idx < 4096; idx += 256) {
        int ww = idx >> 6, c2 = (idx & 63) * 2;
        unsigned lo = f2bf(tile[c2][ww]);
        unsigned hi = f2bf(tile[c2 + 1][ww]);
        dst[idx] = lo | (hi << 16);
    }
}

// ------------------------------------------------------------------
// Kernel C: fully fused deformable conv. Block = (b,ho) row, 512 thr.
// Phase A: offset conv (M=64 pos, N=32 oc-padded, K=1152) -> s_off LDS.
// Phase B: bilinear meta (corner offsets + mask-folded weights).
// Main:    software-pipelined: issue gathers(kk+1) || MFMA(kk) from
//          double-buffered swizzled s_tile; one barrier per kk.
// ------------------------------------------------------------------
__global__ __launch_bounds__(512, 4) void deform_fused(
    const __hip_bfloat16* __restrict__ xT,
    const unsigned short* __restrict__ wT,
    const unsigned short* __restrict__ woffT,
    float* __restrict__ out) {
    __shared__ unsigned short s_tile[2][8192];  // dbuf [64 pos][128 c], XOR-16B swizzle
    __shared__ float  s_off[18][64];            // [oc][pos] offsets
    __shared__ int4   s_pix[576];               // [kk][pos] corner byte offsets
    __shared__ float4 s_wt[576];                // [kk][pos] mask-folded weights

    int blk = blockIdx.x;                // b*64 + ho
    int b = blk >> 6, ho = blk & 63;
    int t = threadIdx.x, l = t & 63, w = t >> 6;
    int lr = l & 15, lg = l >> 4;
    const char* xb = (const char*)xT + (size_t)b * 1048576;

    // ---- Phase A: offset conv. Wave w -> frag (m4 = w>>1, n2 = w&1). ----
    {
        int m4 = w >> 1, n2 = w & 1;
        f32x4 oacc = {0.f, 0.f, 0.f, 0.f};
        for (int kk = 0; kk < 9; ++kk) {
            int y = ho + kk / 3 - 1;
            if ((unsigned)y >= 64u) continue;          // zero A row: skip
            int xcol = m4 * 16 + lr + kk % 3 - 1;
            bool vx = (unsigned)xcol < 64u;
            const unsigned short* wo = woffT + (kk * 32 + n2 * 16 + lr) * 128 + lg * 8;
#pragma unroll
            for (int kg = 0; kg < 4; ++kg) {
                bf16x8 A = {};
                if (vx) A = *(const bf16x8*)(xb + ((y * 64 + xcol) * 128 + kg * 32 + lg * 8) * 2);
                bf16x8 Bf = *(const bf16x8*)(wo + kg * 32);
                oacc = __builtin_amdgcn_mfma_f32_16x16x32_bf16(A, Bf, oacc, 0, 0, 0);
            }
        }
        int oc = n2 * 16 + lr;                 // D: col = oc, row = pos
        if (oc < 18) {
#pragma unroll
            for (int r = 0; r < 4; ++r)
                s_off[oc][m4 * 16 + lg * 4 + r] = oacc[r];
        }
    }
    __syncthreads();

    // ---- Phase B: bilinear meta for all (kk, pos) ----
    for (int e = t; e < 576; e += 512) {
        int pos = e & 63, kk = e >> 6;
        float dy = s_off[2 * kk][pos], dx = s_off[2 * kk + 1][pos];
        float py = (float)(ho + kk / 3 - 1) + dy;
        float px = (float)(pos + kk % 3 - 1) + dx;
        float y0f = floorf(py), x0f = floorf(px);
        float ly = py - y0f, lx = px - x0f;
        int y0 = (int)y0f, x0 = (int)x0f;
        int y1 = y0 + 1, x1 = x0 + 1;
        float my0 = ((unsigned)y0 < 64u) ? 1.f : 0.f;
        float my1 = ((unsigned)y1 < 64u) ? 1.f : 0.f;
        float mx0 = ((unsigned)x0 < 64u) ? 1.f : 0.f;
        float mx1 = ((unsigned)x1 < 64u) ? 1.f : 0.f;
        int y0c = min(max(y0, 0), 63), y1c = min(max(y1, 0), 63);
        int x0c = min(max(x0, 0), 63), x1c = min(max(x1, 0), 63);
        s_pix[e] = make_int4((y0c * 64 + x0c) * 256, (y0c * 64 + x1c) * 256,
                             (y1c * 64 + x0c) * 256, (y1c * 64 + x1c) * 256);
        s_wt[e] = make_float4((1.f - ly) * (1.f - lx) * my0 * mx0,
                              (1.f - ly) * lx * my0 * mx1,
                              ly * (1.f - lx) * my1 * mx0,
                              ly * lx * my1 * mx1);
    }
    __syncthreads();

    // ---- Main pipelined loop ----
    int pg = t >> 5;          // pos group 0..15
    int cq = t & 31;          // c-quad
    int cb = w * 16;          // wave's cout base
    int coff = cq * 8;
    f32x4 acc[4] = {{0.f,0.f,0.f,0.f},{0.f,0.f,0.f,0.f},{0.f,0.f,0.f,0.f},{0.f,0.f,0.f,0.f}};
    uint2 u[4][4];            // in-flight gathers (static-indexed only)

    auto issue = [&](int kk) {
#pragma unroll
        for (int i = 0; i < 4; ++i) {
            int pos = pg + i * 16;
            int4 pix = s_pix[kk * 64 + pos];
            u[i][0] = *(const uint2*)(xb + pix.x + coff);
            u[i][1] = *(const uint2*)(xb + pix.y + coff);
            u[i][2] = *(const uint2*)(xb + pix.z + coff);
            u[i][3] = *(const uint2*)(xb + pix.w + coff);
        }
    };
    auto process = [&](int kk, int buf) {
        char* tp = (char*)s_tile[buf];
#pragma unroll
        for (int i = 0; i < 4; ++i) {
            int pos = pg + i * 16;
            float4 wt = s_wt[kk * 64 + pos];
            float r0 = wt.x * bflo(u[i][0].x) + wt.y * bflo(u[i][1].x) + wt.z * bflo(u[i][2].x) + wt.w * bflo(u[i][3].x);
            float r1 = wt.x * bfhi(u[i][0].x) + wt.y * bfhi(u[i][1].x) + wt.z * bfhi(u[i][2].x) + wt.w * bfhi(u[i][3].x);
            float r2 = wt.x * bflo(u[i][0].y) + wt.y * bflo(u[i][1].y) + wt.z * bflo(u[i][2].y) + wt.w * bflo(u[i][3].y);
            float r3 = wt.x * bfhi(u[i][0].y) + wt.y * bfhi(u[i][1].y) + wt.z * bfhi(u[i][2].y) + wt.w * bfhi(u[i][3].y);
            uint2 o;
            o.x = (unsigned)f2bf(r0) | ((unsigned)f2bf(r1) << 16);
            o.y = (unsigned)f2bf(r2) | ((unsigned)f2bf(r3) << 16);
            *(uint2*)(tp + pos * 256 + (((cq >> 1) ^ (pos & 7)) << 4) + (cq & 1) * 8) = o;
        }
    };

    // prologue
    issue(0);
    process(0, 0);
    __syncthreads();

    for (int kk = 0; kk < 9; ++kk) {
        if (kk < 8) issue(kk + 1);                   // gathers in flight over MFMA
        // A-frags (L2-resident wT) + MFMA from buf[kk&1]
        {
            const unsigned short* wr = wT + ((kk * 128 + cb + lr) << 7) + lg * 8;
            bf16x8 Af[4];
#pragma unroll
            for (int kg = 0; kg < 4; ++kg)
                Af[kg] = *(const bf16x8*)(wr + kg * 32);
            char* rp = (char*)s_tile[kk & 1];
#pragma unroll
            for (int kg = 0; kg < 4; ++kg) {
                int slot = kg * 4 + lg;
#pragma unroll
                for (int n = 0; n < 4; ++n) {
                    int row = n * 16 + lr;
                    bf16x8 Bf = *(const bf16x8*)(rp + row * 256 + ((slot ^ (row & 7)) << 4));
                    acc[n] = __builtin_amdgcn_mfma_f32_16x16x32_bf16(Af[kg], Bf, acc[n], 0, 0, 0);
                }
            }
        }
        if (kk < 8) process(kk + 1, (kk + 1) & 1);   // blend + write other buffer
        __syncthreads();
    }

    // Epilogue: D row = cout = cb + lg*4 + r, col = pos = n*16 + lr
    float* ob = out + ((size_t)(b * 128 + cb + lg * 4)) * 4096 + ho * 64;
#pragma unroll
    for (int n = 0; n < 4; ++n) {
#pragma unroll
        for (int r = 0; r < 4; ++r)
            ob[r * 4096 + n * 16 + lr] = acc[n][r];
    }
}

// ------------------------------------------------------------------
extern "C" void kernel_launch(void* const* d_in, const int* in_sizes, int n_in,
                              void* d_out, int out_size, void* d_ws, size_t ws_size,
                              hipStream_t stream) {
    const float* x    = (const float*)d_in[0];
    const float* woff = (const float*)d_in[1];
    const float* w    = (const float*)d_in[2];
    float* out = (float*)d_out;

    unsigned short* wT    = (unsigned short*)d_ws;                    // 294,912 B
    unsigned short* woffT = (unsigned short*)((char*)d_ws + 294912);  //  73,728 B
    __hip_bfloat16* xT    = (__hip_bfloat16*)((char*)d_ws + 368640);  // 8,388,608 B

    prep_weights<<<576, 256, 0, stream>>>(w, woff, wT, woffT);
    transpose_nchw_nhwc<<<512, 256, 0, stream>>>(x, (unsigned*)xT);
    deform_fused<<<512, 512, 0, stream>>>(xT, wT, woffT, out);
}

// Round 7
// 146.198 us; speedup vs baseline: 1.0209x; 1.0209x over previous
//
#include <hip/hip_runtime.h>
#include <hip/hip_bf16.h>
#include <math.h>

// B=8, Cin=Cout=128, H=W=64, K=3, S=1, P=1
// ws layout (total 8,757,248 B < proven-safe 10,747,904 B):
//   wT    bf16 [9][128 co][128 c]  @ 0        (294,912 B)
//   woffT bf16 [9][32 oc][128 c]   @ 294,912  ( 73,728 B)  oc>=18 zero
//   xT    bf16 [8][64][64][128]    @ 368,640  (8,388,608 B)

typedef short bf16x8 __attribute__((ext_vector_type(8)));
typedef float f32x4  __attribute__((ext_vector_type(4)));

__device__ __forceinline__ unsigned short f2bf(float f) {
    unsigned u = __float_as_uint(f);
    u += 0x7fffu + ((u >> 16) & 1u);           // RNE
    return (unsigned short)(u >> 16);
}
__device__ __forceinline__ float bflo(unsigned u) { return __uint_as_float(u << 16); }
__device__ __forceinline__ float bfhi(unsigned u) { return __uint_as_float(u & 0xffff0000u); }

// ------------------------------------------------------------------
// Kernel P: repack w / w_offset into MFMA-fragment-ready bf16.
// ------------------------------------------------------------------
__global__ __launch_bounds__(256) void prep_weights(
    const float* __restrict__ w, const float* __restrict__ woff,
    unsigned short* __restrict__ wT, unsigned short* __restrict__ woffT) {
    int idx = blockIdx.x * 256 + threadIdx.x;
    if (idx < 147456) {
        int c  = idx & 127;
        int co = (idx >> 7) & 127;
        int kk = idx >> 14;
        wT[idx] = f2bf(w[co * 1152 + c * 9 + kk]);
    }
    if (idx < 36864) {
        int c  = idx & 127;
        int oc = (idx >> 7) & 31;
        int kk = idx >> 12;
        woffT[idx] = (oc < 18) ? f2bf(woff[oc * 1152 + c * 9 + kk]) : (unsigned short)0;
    }
}

// ------------------------------------------------------------------
// Kernel A: NCHW fp32 -> NHWC bf16 (pair-packed uint writes).
// ------------------------------------------------------------------
__global__ __launch_bounds__(256) void transpose_nchw_nhwc(
    const float* __restrict__ x, unsigned* __restrict__ xT) {
    __shared__ float tile[128][65];
    int bh = blockIdx.x;                 // b*64 + h
    int b = bh >> 6, h = bh & 63;
    const float* src = x + b * 524288 + h * 64;
    for (int idx = threadIdx.x; idx < 8192; idx += 256) {
        int c = idx >> 6, ww = idx & 63;
        tile[c][ww] = src[c * 4096 + ww];
    }
    __syncthreads();
    unsigned* dst = xT + (size_t)bh * 4096;   // [w][c/2] as uint
    for (int idx = threadIdx.x; idx < 4096; idx += 256) {
        int ww = idx >> 6, c2 = (idx & 63) * 2;
        unsigned lo = f2bf(tile[c2][ww]);
        unsigned hi = f2bf(tile[c2 + 1][ww]);
        dst[idx] = lo | (hi << 16);
    }
}

// ------------------------------------------------------------------
// Kernel C: fused deformable conv. Block = (b,ho) row, 512 thr.
// XCD-aware swizzle: b = blockIdx&7 so each XCD's resident blocks share
// one batch -> per-XCD L2 working set ~1.4 MB (fits 4 MB).
// Phase A: offset conv -> s_off. Phase B: bilinear meta.
// Main: pipelined issue(kk+1) | MFMA(kk) | process(kk+1), prefetch pinned
// by sched_barrier(0) fences so gathers stay in flight over the MFMAs.
// ------------------------------------------------------------------
__global__ __launch_bounds__(512, 4) void deform_fused(
    const __hip_bfloat16* __restrict__ xT,
    const unsigned short* __restrict__ wT,
    const unsigned short* __restrict__ woffT,
    float* __restrict__ out) {
    __shared__ unsigned short s_tile[2][8192];  // dbuf [64 pos][128 c], XOR-16B swizzle
    __shared__ float  s_off[18][64];            // [oc][pos] offsets
    __shared__ int4   s_pix[576];               // [kk][pos] corner byte offsets
    __shared__ float4 s_wt[576];                // [kk][pos] mask-folded weights

    int raw = blockIdx.x;
    int b  = raw & 7;                    // XCD-locality: batch == XCD
    int ho = raw >> 3;
    int t = threadIdx.x, l = t & 63, w = t >> 6;
    int lr = l & 15, lg = l >> 4;
    const char* xb = (const char*)xT + (size_t)b * 1048576;

    // ---- Phase A: offset conv. Wave w -> frag (m4 = w>>1, n2 = w&1). ----
    {
        int m4 = w >> 1, n2 = w & 1;
        f32x4 oacc = {0.f, 0.f, 0.f, 0.f};
        for (int kk = 0; kk < 9; ++kk) {
            int y = ho + kk / 3 - 1;
            if ((unsigned)y >= 64u) continue;          // zero A row: skip
            int xcol = m4 * 16 + lr + kk % 3 - 1;
            bool vx = (unsigned)xcol < 64u;
            const unsigned short* wo = woffT + (kk * 32 + n2 * 16 + lr) * 128 + lg * 8;
#pragma unroll
            for (int kg = 0; kg < 4; ++kg) {
                bf16x8 A = {};
                if (vx) A = *(const bf16x8*)(xb + ((y * 64 + xcol) * 128 + kg * 32 + lg * 8) * 2);
                bf16x8 Bf = *(const bf16x8*)(wo + kg * 32);
                oacc = __builtin_amdgcn_mfma_f32_16x16x32_bf16(A, Bf, oacc, 0, 0, 0);
            }
        }
        int oc = n2 * 16 + lr;                 // D: col = oc, row = pos
        if (oc < 18) {
#pragma unroll
            for (int r = 0; r < 4; ++r)
                s_off[oc][m4 * 16 + lg * 4 + r] = oacc[r];
        }
    }
    __syncthreads();

    // ---- Phase B: bilinear meta for all (kk, pos) ----
    for (int e = t; e < 576; e += 512) {
        int pos = e & 63, kk = e >> 6;
        float dy = s_off[2 * kk][pos], dx = s_off[2 * kk + 1][pos];
        float py = (float)(ho + kk / 3 - 1) + dy;
        float px = (float)(pos + kk % 3 - 1) + dx;
        float y0f = floorf(py), x0f = floorf(px);
        float ly = py - y0f, lx = px - x0f;
        int y0 = (int)y0f, x0 = (int)x0f;
        int y1 = y0 + 1, x1 = x0 + 1;
        float my0 = ((unsigned)y0 < 64u) ? 1.f : 0.f;
        float my1 = ((unsigned)y1 < 64u) ? 1.f : 0.f;
        float mx0 = ((unsigned)x0 < 64u) ? 1.f : 0.f;
        float mx1 = ((unsigned)x1 < 64u) ? 1.f : 0.f;
        int y0c = min(max(y0, 0), 63), y1c = min(max(y1, 0), 63);
        int x0c = min(max(x0, 0), 63), x1c = min(max(x1, 0), 63);
        s_pix[e] = make_int4((y0c * 64 + x0c) * 256, (y0c * 64 + x1c) * 256,
                             (y1c * 64 + x0c) * 256, (y1c * 64 + x1c) * 256);
        s_wt[e] = make_float4((1.f - ly) * (1.f - lx) * my0 * mx0,
                              (1.f - ly) * lx * my0 * mx1,
                              ly * (1.f - lx) * my1 * mx0,
                              ly * lx * my1 * mx1);
    }
    __syncthreads();

    // ---- Main pipelined loop ----
    int pg = t >> 5;          // pos group 0..15
    int cq = t & 31;          // c-quad
    int cb = w * 16;          // wave's cout base
    int coff = cq * 8;
    f32x4 acc[4] = {{0.f,0.f,0.f,0.f},{0.f,0.f,0.f,0.f},{0.f,0.f,0.f,0.f},{0.f,0.f,0.f,0.f}};
    uint2 u[4][4];            // in-flight gathers (static-indexed only)

    auto issue = [&](int kk) {
#pragma unroll
        for (int i = 0; i < 4; ++i) {
            int pos = pg + i * 16;
            int4 pix = s_pix[kk * 64 + pos];
            u[i][0] = *(const uint2*)(xb + pix.x + coff);
            u[i][1] = *(const uint2*)(xb + pix.y + coff);
            u[i][2] = *(const uint2*)(xb + pix.z + coff);
            u[i][3] = *(const uint2*)(xb + pix.w + coff);
        }
    };
    auto process = [&](int kk, int buf) {
        char* tp = (char*)s_tile[buf];
#pragma unroll
        for (int i = 0; i < 4; ++i) {
            int pos = pg + i * 16;
            float4 wt = s_wt[kk * 64 + pos];
            float r0 = wt.x * bflo(u[i][0].x) + wt.y * bflo(u[i][1].x) + wt.z * bflo(u[i][2].x) + wt.w * bflo(u[i][3].x);
            float r1 = wt.x * bfhi(u[i][0].x) + wt.y * bfhi(u[i][1].x) + wt.z * bfhi(u[i][2].x) + wt.w * bfhi(u[i][3].x);
            float r2 = wt.x * bflo(u[i][0].y) + wt.y * bflo(u[i][1].y) + wt.z * bflo(u[i][2].y) + wt.w * bflo(u[i][3].y);
            float r3 = wt.x * bfhi(u[i][0].y) + wt.y * bfhi(u[i][1].y) + wt.z * bfhi(u[i][2].y) + wt.w * bfhi(u[i][3].y);
            uint2 o;
            o.x = (unsigned)f2bf(r0) | ((unsigned)f2bf(r1) << 16);
            o.y = (unsigned)f2bf(r2) | ((unsigned)f2bf(r3) << 16);
            *(uint2*)(tp + pos * 256 + (((cq >> 1) ^ (pos & 7)) << 4) + (cq & 1) * 8) = o;
        }
    };

    // prologue
    issue(0);
    process(0, 0);
    __syncthreads();

    for (int kk = 0; kk < 9; ++kk) {
        if (kk < 8) issue(kk + 1);                   // gathers in flight over MFMA
        __builtin_amdgcn_sched_barrier(0);           // pin: loads stay ABOVE MFMAs
        // A-frags (L2-resident wT) + MFMA from buf[kk&1]
        {
            const unsigned short* wr = wT + ((kk * 128 + cb + lr) << 7) + lg * 8;
            bf16x8 Af[4];
#pragma unroll
            for (int kg = 0; kg < 4; ++kg)
                Af[kg] = *(const bf16x8*)(wr + kg * 32);
            char* rp = (char*)s_tile[kk & 1];
#pragma unroll
            for (int kg = 0; kg < 4; ++kg) {
                int slot = kg * 4 + lg;
#pragma unroll
                for (int n = 0; n < 4; ++n) {
                    int row = n * 16 + lr;
                    bf16x8 Bf = *(const bf16x8*)(rp + row * 256 + ((slot ^ (row & 7)) << 4));
                    acc[n] = __builtin_amdgcn_mfma_f32_16x16x32_bf16(Af[kg], Bf, acc[n], 0, 0, 0);
                }
            }
        }
        __builtin_amdgcn_sched_barrier(0);           // pin: blend stays BELOW MFMAs
        if (kk < 8) process(kk + 1, (kk + 1) & 1);   // blend + write other buffer
        __syncthreads();
    }

    // Epilogue: D row = cout = cb + lg*4 + r, col = pos = n*16 + lr
    float* ob = out + ((size_t)(b * 128 + cb + lg * 4)) * 4096 + ho * 64;
#pragma unroll
    for (int n = 0; n < 4; ++n) {
#pragma unroll
        for (int r = 0; r < 4; ++r)
            ob[r * 4096 + n * 16 + lr] = acc[n][r];
    }
}

// ------------------------------------------------------------------
extern "C" void kernel_launch(void* const* d_in, const int* in_sizes, int n_in,
                              void* d_out, int out_size, void* d_ws, size_t ws_size,
                              hipStream_t stream) {
    const float* x    = (const float*)d_in[0];
    const float* woff = (const float*)d_in[1];
    const float* w    = (const float*)d_in[2];
    float* out = (float*)d_out;

    unsigned short* wT    = (unsigned short*)d_ws;                    // 294,912 B
    unsigned short* woffT = (unsigned short*)((char*)d_ws + 294912);  //  73,728 B
    __hip_bfloat16* xT    = (__hip_bfloat16*)((char*)d_ws + 368640);  // 8,388,608 B

    prep_weights<<<576, 256, 0, stream>>>(w, woff, wT, woffT);
    transpose_nchw_nhwc<<<512, 256, 0, stream>>>(x, (unsigned*)xT);
    deform_fused<<<512, 512, 0, stream>>>(xT, wT, woffT, out);
}